// Round 1
// 2041.671 us; speedup vs baseline: 1.7463x; 1.7463x over previous
//
#include <hip/hip_runtime.h>
#include <hip/hip_bf16.h>

#define B_   4
#define LD_  1024
#define LE_  1024
#define D_   256
#define H_   8
#define DK_  32
#define DFF_ 1024
#define NL_  6
#define NTOK (B_ * LD_)   // 4096 decoder tokens; encoder also 4*1024 = 4096

typedef __hip_bfloat16 bf16;
typedef __bf16 bf16_t;
typedef bf16_t bf16x8 __attribute__((ext_vector_type(8)));
typedef float  f32x4  __attribute__((ext_vector_type(4)));

__device__ __forceinline__ float bits2f(unsigned short u) {
    union { unsigned int i; float f; } w; w.i = ((unsigned int)u) << 16; return w.f;
}
// dtype-flexible scalar load from tensor base + element index
__device__ __forceinline__ float ldx(const void* p, size_t i, int f32) {
    if (f32) return ((const float*)p)[i];
    return bits2f(((const unsigned short*)p)[i]);
}

// ---------------------------------------------------------------------------
// Detect input dtype (bf16 vs fp32). flag: 1=fp32, 0=bf16.
__global__ __launch_bounds__(256) void detect_kernel(
    const void* __restrict__ enc, int* __restrict__ flag)
{
    __shared__ int bad;
    if (threadIdx.x == 0) bad = 0;
    __syncthreads();
    const unsigned short* u = (const unsigned short*)enc;
    int b = 0;
    for (int i = threadIdx.x; i < 4096; i += 256) {
        unsigned short e = (u[i] >> 7) & 0xFF;
        if (e >= 142) b = 1;
    }
    if (b) atomicOr(&bad, 1);
    __syncthreads();
    if (threadIdx.x == 0) *flag = bad;
}

// ---------------------------------------------------------------------------
__global__ __launch_bounds__(256) void embed_kernel(
    const void* __restrict__ dec, const void* __restrict__ Wt,
    const void* __restrict__ bt, float* __restrict__ x, const int* __restrict__ flag)
{
    int f32 = *flag;
    int i = blockIdx.x * 256 + threadIdx.x;     // over NTOK * D_
    int d = i & (D_ - 1);
    int t = i >> 8;
    float a0 = ldx(dec, t * 3 + 0, f32);
    float a1 = ldx(dec, t * 3 + 1, f32);
    float a2 = ldx(dec, t * 3 + 2, f32);
    x[i] = ldx(bt, d, f32) + a0 * ldx(Wt, 0 * D_ + d, f32)
         + a1 * ldx(Wt, 1 * D_ + d, f32) + a2 * ldx(Wt, 2 * D_ + d, f32);
}

__global__ __launch_bounds__(256) void conv_kernel(
    const void* __restrict__ in, float* __restrict__ out, const int* __restrict__ flag)
{
    int f32 = *flag;
    int i = blockIdx.x * 256 + threadIdx.x;
    out[i] = ldx(in, i, f32);
}

__global__ __launch_bounds__(256) void add_pe_kernel(float* __restrict__ x)
{
    int i = blockIdx.x * 256 + threadIdx.x;
    int d = i & (D_ - 1);
    int tok = i >> 8;
    int pos = tok & (LD_ - 1);
    int j = d & 127;
    float inv = powf(10000.0f, -2.0f * (float)j / (float)D_);
    float s = (float)pos * inv;
    float pe = (d < 128) ? sinf(s) : cosf(s);
    x[i] += pe;
}

// ---------------------------------------------------------------------------
// C = A @ W + bias (optional relu). A fp32 [M,K]; W,bias dtype per flag;
// wOff/bOff are ELEMENT offsets of the layer slice within the weight tensor.
// z-batched over up to 3 independent (A,W,bias,C) tuples.
__global__ __launch_bounds__(256) void gemm3_kernel(
    const float* __restrict__ A0, const float* __restrict__ A1, const float* __restrict__ A2,
    const void* __restrict__ W0, const void* __restrict__ W1, const void* __restrict__ W2,
    const void* __restrict__ bias0, const void* __restrict__ bias1, const void* __restrict__ bias2,
    float* __restrict__ C0, float* __restrict__ C1, float* __restrict__ C2,
    size_t wOff, size_t bOff,
    int M, int N, int K, int relu, const int* __restrict__ flag)
{
    int f32 = *flag;
    int z = blockIdx.z;
    const float* A = (z == 0) ? A0 : (z == 1) ? A1 : A2;
    const void*  W = (z == 0) ? W0 : (z == 1) ? W1 : W2;
    const void*  bias = (z == 0) ? bias0 : (z == 1) ? bias1 : bias2;
    float* C = (z == 0) ? C0 : (z == 1) ? C1 : C2;

    __shared__ float As[64][20];
    __shared__ float Bs[16][68];

    int tid = threadIdx.x;
    int tx = tid & 15, ty = tid >> 4;
    int m0 = blockIdx.y * 64, n0 = blockIdx.x * 64;

    int arow = tid >> 2;            // 0..63
    int acol = (tid & 3) * 4;       // 0..12
    int brow = ty;                  // 0..15
    int bcol = tx * 4;              // 0..60

    float c[4][4] = {};

    for (int k0 = 0; k0 < K; k0 += 16) {
        float4 av = *(const float4*)&A[(size_t)(m0 + arow) * K + k0 + acol];
        size_t widx = wOff + (size_t)(k0 + brow) * N + n0 + bcol;
        float4 bv;
        if (f32) {
            bv = *(const float4*)((const float*)W + widx);
        } else {
            ushort4 wv = *(const ushort4*)((const unsigned short*)W + widx);
            bv = make_float4(bits2f(wv.x), bits2f(wv.y), bits2f(wv.z), bits2f(wv.w));
        }

        __syncthreads();
        *(float4*)&As[arow][acol] = av;
        *(float4*)&Bs[brow][bcol] = bv;
        __syncthreads();

#pragma unroll
        for (int k = 0; k < 16; ++k) {
            float a0 = As[ty][k], a1 = As[ty + 16][k], a2 = As[ty + 32][k], a3 = As[ty + 48][k];
            float b0 = Bs[k][tx], b1 = Bs[k][tx + 16], b2 = Bs[k][tx + 32], b3 = Bs[k][tx + 48];
            c[0][0] += a0 * b0; c[0][1] += a0 * b1; c[0][2] += a0 * b2; c[0][3] += a0 * b3;
            c[1][0] += a1 * b0; c[1][1] += a1 * b1; c[1][2] += a1 * b2; c[1][3] += a1 * b3;
            c[2][0] += a2 * b0; c[2][1] += a2 * b1; c[2][2] += a2 * b2; c[2][3] += a2 * b3;
            c[3][0] += a3 * b0; c[3][1] += a3 * b1; c[3][2] += a3 * b2; c[3][3] += a3 * b3;
        }
    }

#pragma unroll
    for (int i = 0; i < 4; ++i) {
        int m = m0 + ty + 16 * i;
#pragma unroll
        for (int j = 0; j < 4; ++j) {
            int n = n0 + tx + 16 * j;
            float v = c[i][j] + ldx(bias, bOff + n, f32);
            if (relu) v = fmaxf(v, 0.0f);
            C[(size_t)m * N + n] = v;
        }
    }
}

// ---------------------------------------------------------------------------
// MFMA flash attention. One block per (64-q-row tile, head, batch).
// grid = (LD/64, H, B), 256 threads = 4 waves; wave w owns q rows w*16..w*16+15.
//
// Numerics: S = Q·K^T computed with split-bf16 (hi/lo) -> fp32-equivalent
// scores (rel err ~2^-16); softmax fully fp32 in registers; P,V single bf16
// with fp32 MFMA accumulation (noise ~2^-9 relative on a small ctx term).
//
// Fragment layouts (v_mfma_f32_16x16x32_bf16, learn_hip-verified):
//   A: row = lane&15, k = 8*(lane>>4)+j (contiguous 8)
//   B: col = lane&15, k = 8*(lane>>4)+j (contiguous 8)
//   C/D: col = lane&15, row = 4*(lane>>4)+reg
__global__ __launch_bounds__(256) void fattn_mfma_kernel(
    const float* __restrict__ Q, const float* __restrict__ K,
    const float* __restrict__ V, float* __restrict__ O,
    const int* __restrict__ mask, int causal)
{
    // K hi/lo: [key][dim], row stride 40 bf16 = 80 B (16B-mult, 2-way banks max)
    __shared__ __align__(16) bf16_t Khi[64][40];
    __shared__ __align__(16) bf16_t Klo[64][40];
    // V transposed: [dv][kv], row stride 72 bf16 = 144 B (16B-mult)
    __shared__ __align__(16) bf16_t Vt[32][72];
    // P transpose buffer, per-wave private: [wave][qrow][kv], stride 68 f32 = 272 B
    __shared__ __align__(16) float Ps[4][16][68];
    __shared__ int smask[64];

    const int tid = threadIdx.x;
    const int qt = blockIdx.x, h = blockIdx.y, b = blockIdx.z;
    const int w   = tid >> 6;        // wave 0..3
    const int l   = tid & 63;
    const int l15 = l & 15;
    const int lg  = l >> 4;          // 0..3

    // staging loader mapping: 4 lanes per row, 8 elems per lane
    const int lr = tid >> 2;         // 0..63
    const int lc = (tid & 3) * 8;    // 0,8,16,24

    // ---- Q fragment (scale folded in, hi/lo split), held in regs ----
    const float scale = 0.17677669529663687f;   // 1/sqrt(32)
    bf16x8 qhi, qlo;
    {
        const float* qp = Q + ((size_t)(b * LD_ + qt * 64 + w * 16 + l15)) * D_ + h * DK_ + 8 * lg;
        float4 qa = *(const float4*)qp;
        float4 qb = *(const float4*)(qp + 4);
        float qf[8] = {qa.x, qa.y, qa.z, qa.w, qb.x, qb.y, qb.z, qb.w};
#pragma unroll
        for (int j = 0; j < 8; ++j) {
            float xv = qf[j] * scale;
            bf16_t hv = (bf16_t)xv;
            qhi[j] = hv;
            qlo[j] = (bf16_t)(xv - (float)hv);
        }
    }

    float mrow[4], lsum[4];
#pragma unroll
    for (int r = 0; r < 4; ++r) { mrow[r] = -3.0e38f; lsum[r] = 0.0f; }
    f32x4 o0 = {0.f, 0.f, 0.f, 0.f};   // dv 0..15,  rows 4*lg+r
    f32x4 o1 = {0.f, 0.f, 0.f, 0.f};   // dv 16..31

    const int nkt = causal ? (qt + 1) : (LE_ / 64);

    for (int kt = 0; kt < nkt; ++kt) {
        __syncthreads();    // all waves done with previous K/V tile
        // ---- stage K (hi/lo bf16) and V^T (bf16) ----
        {
            const float* kp = K + ((size_t)(b * LE_ + kt * 64 + lr)) * D_ + h * DK_ + lc;
            const float* vp = V + ((size_t)(b * LE_ + kt * 64 + lr)) * D_ + h * DK_ + lc;
            float4 ka = *(const float4*)kp;
            float4 kb = *(const float4*)(kp + 4);
            float kf[8] = {ka.x, ka.y, ka.z, ka.w, kb.x, kb.y, kb.z, kb.w};
            bf16x8 khv, klv;
#pragma unroll
            for (int j = 0; j < 8; ++j) {
                bf16_t hv = (bf16_t)kf[j];
                khv[j] = hv;
                klv[j] = (bf16_t)(kf[j] - (float)hv);
            }
            *(bf16x8*)&Khi[lr][lc] = khv;
            *(bf16x8*)&Klo[lr][lc] = klv;
            float4 va = *(const float4*)vp;
            float4 vb = *(const float4*)(vp + 4);
            float vf[8] = {va.x, va.y, va.z, va.w, vb.x, vb.y, vb.z, vb.w};
#pragma unroll
            for (int j = 0; j < 8; ++j)
                Vt[lc + j][lr] = (bf16_t)vf[j];
            if (tid < 64) smask[tid] = mask[b * 1024 + kt * 64 + tid];
        }
        __syncthreads();

        // ---- S = Q·K^T (split bf16: qh*kh + qh*kl + ql*kh) ----
        f32x4 s[4];
#pragma unroll
        for (int nt = 0; nt < 4; ++nt) {
            bf16x8 kh = *(const bf16x8*)&Khi[nt * 16 + l15][8 * lg];
            bf16x8 kl = *(const bf16x8*)&Klo[nt * 16 + l15][8 * lg];
            f32x4 acc = {0.f, 0.f, 0.f, 0.f};
            acc = __builtin_amdgcn_mfma_f32_16x16x32_bf16(qhi, kh, acc, 0, 0, 0);
            acc = __builtin_amdgcn_mfma_f32_16x16x32_bf16(qhi, kl, acc, 0, 0, 0);
            acc = __builtin_amdgcn_mfma_f32_16x16x32_bf16(qlo, kh, acc, 0, 0, 0);
            s[nt] = acc;
        }

        // ---- mask + online softmax (rows 4*lg+r, fp32 in regs) ----
        const int row0 = qt * 64 + w * 16 + 4 * lg;
        float pm[4] = {-3.0e38f, -3.0e38f, -3.0e38f, -3.0e38f};
#pragma unroll
        for (int nt = 0; nt < 4; ++nt) {
            int col = kt * 64 + nt * 16 + l15;
            int msk = smask[nt * 16 + l15];
#pragma unroll
            for (int r = 0; r < 4; ++r) {
                bool dead = (msk != 0) || (causal && col > row0 + r);
                float v = dead ? -1e30f : s[nt][r];
                s[nt][r] = v;
                pm[r] = fmaxf(pm[r], v);
            }
        }
#pragma unroll
        for (int r = 0; r < 4; ++r) {
            pm[r] = fmaxf(pm[r], __shfl_xor(pm[r], 1));
            pm[r] = fmaxf(pm[r], __shfl_xor(pm[r], 2));
            pm[r] = fmaxf(pm[r], __shfl_xor(pm[r], 4));
            pm[r] = fmaxf(pm[r], __shfl_xor(pm[r], 8));
        }
        float alpha[4], psum[4];
#pragma unroll
        for (int r = 0; r < 4; ++r) {
            float mnew = fmaxf(mrow[r], pm[r]);
            alpha[r] = __expf(mrow[r] - mnew);
            mrow[r] = mnew;
            psum[r] = 0.0f;
        }
#pragma unroll
        for (int nt = 0; nt < 4; ++nt) {
#pragma unroll
            for (int r = 0; r < 4; ++r) {
                float p = __expf(s[nt][r] - mrow[r]);
                Ps[w][4 * lg + r][nt * 16 + l15] = p;
                psum[r] += p;
            }
        }
#pragma unroll
        for (int r = 0; r < 4; ++r) {
            psum[r] += __shfl_xor(psum[r], 1);
            psum[r] += __shfl_xor(psum[r], 2);
            psum[r] += __shfl_xor(psum[r], 4);
            psum[r] += __shfl_xor(psum[r], 8);
            lsum[r] = lsum[r] * alpha[r] + psum[r];
            o0[r] *= alpha[r];
            o1[r] *= alpha[r];
        }

        // ---- O += P·V  (P transposed through wave-private LDS; same-wave
        //      ds ordering is in-order, no barrier needed) ----
#pragma unroll
        for (int pass = 0; pass < 2; ++pass) {
            const float* pr = &Ps[w][l15][pass * 32 + 8 * lg];
            f32x4 pa0 = *(const f32x4*)pr;
            f32x4 pa1 = *(const f32x4*)(pr + 4);
            bf16x8 pa;
#pragma unroll
            for (int j = 0; j < 4; ++j) {
                pa[j]     = (bf16_t)pa0[j];
                pa[4 + j] = (bf16_t)pa1[j];
            }
            bf16x8 vb0 = *(const bf16x8*)&Vt[l15][pass * 32 + 8 * lg];
            bf16x8 vb1 = *(const bf16x8*)&Vt[16 + l15][pass * 32 + 8 * lg];
            o0 = __builtin_amdgcn_mfma_f32_16x16x32_bf16(pa, vb0, o0, 0, 0, 0);
            o1 = __builtin_amdgcn_mfma_f32_16x16x32_bf16(pa, vb1, o1, 0, 0, 0);
        }
    }

    // ---- epilogue: normalize and store (rows 4*lg+r, cols l15 / l15+16) ----
    float inv[4];
#pragma unroll
    for (int r = 0; r < 4; ++r) inv[r] = 1.0f / lsum[r];
    float* op = O + ((size_t)(b * LD_ + qt * 64 + w * 16 + 4 * lg)) * D_ + h * DK_ + l15;
#pragma unroll
    for (int r = 0; r < 4; ++r) {
        op[(size_t)r * D_ + 0]  = o0[r] * inv[r];
        op[(size_t)r * D_ + 16] = o1[r] * inv[r];
    }
}

// ---------------------------------------------------------------------------
// x = LayerNorm(t + x) * g + b ; g/b dtype per flag, gbOff = element offset
__global__ __launch_bounds__(256) void ln_res_kernel(
    const float* __restrict__ t, float* __restrict__ x,
    const void* __restrict__ g, const void* __restrict__ bt,
    size_t gbOff, const int* __restrict__ flag)
{
    __shared__ float r1[256];
    __shared__ float r2[256];
    int f32 = *flag;
    int tok = blockIdx.x;
    int d = threadIdx.x;
    size_t idx = (size_t)tok * D_ + d;
    float v = t[idx] + x[idx];
    r1[d] = v; r2[d] = v * v;
    __syncthreads();
    for (int off = 128; off > 0; off >>= 1) {
        if (d < off) { r1[d] += r1[d + off]; r2[d] += r2[d + off]; }
        __syncthreads();
    }
    float mean = r1[0] * (1.0f / 256.0f);
    float var  = r2[0] * (1.0f / 256.0f) - mean * mean;
    float inv  = 1.0f / sqrtf(var + 1e-5f);
    x[idx] = (v - mean) * inv * ldx(g, gbOff + d, f32) + ldx(bt, gbOff + d, f32);
}

__global__ __launch_bounds__(256) void cast_kernel(
    const float* __restrict__ x, void* __restrict__ out, const int* __restrict__ flag)
{
    int f32 = *flag;
    int i = blockIdx.x * 256 + threadIdx.x;
    if (f32) ((float*)out)[i] = x[i];
    else ((bf16*)out)[i] = __float2bfloat16(x[i]);
}

// ---------------------------------------------------------------------------
extern "C" void kernel_launch(void* const* d_in, const int* in_sizes, int n_in,
                              void* d_out, int out_size, void* d_ws, size_t ws_size,
                              hipStream_t stream)
{
    const void* enc       = d_in[0];
    const void* dec       = d_in[1];
    const int*  enc_masks = (const int*)d_in[2];
    const int*  dec_masks = (const int*)d_in[3];
    const void* W_tgt = d_in[4];
    const void* b_tgt = d_in[5];
    const void* sa_Wq = d_in[6];
    const void* sa_bq = d_in[7];
    const void* sa_Wk = d_in[8];
    const void* sa_bk = d_in[9];
    const void* sa_Wv = d_in[10];
    const void* sa_bv = d_in[11];
    const void* sa_Wo = d_in[12];
    const void* sa_bo = d_in[13];
    const void* sa_ln_g = d_in[14];
    const void* sa_ln_b = d_in[15];
    const void* ca_Wq = d_in[16];
    const void* ca_bq = d_in[17];
    const void* ca_Wk = d_in[18];
    const void* ca_bk = d_in[19];
    const void* ca_Wv = d_in[20];
    const void* ca_bv = d_in[21];
    const void* ca_Wo = d_in[22];
    const void* ca_bo = d_in[23];
    const void* ca_ln_g = d_in[24];
    const void* ca_ln_b = d_in[25];
    const void* ff_W1 = d_in[26];
    const void* ff_b1 = d_in[27];
    const void* ff_W2 = d_in[28];
    const void* ff_b2 = d_in[29];
    const void* ff_ln_g = d_in[30];
    const void* ff_ln_b = d_in[31];

    const size_t M1 = (size_t)NTOK * D_;        // 1M floats
    float* ws = (float*)d_ws;
    float* x     = ws;
    float* q     = ws + 1 * M1;
    float* k     = ws + 2 * M1;
    float* v     = ws + 3 * M1;
    float* ctx   = ws + 4 * M1;
    float* t     = ws + 5 * M1;
    float* h     = ws + 6 * M1;                 // 4M floats (NTOK x DFF)
    float* enc_f = ws + 10 * M1;
    int*   flag  = (int*)(ws + 11 * M1);

    const int nElem = NTOK * D_;                // 1,048,576

    detect_kernel<<<1, 256, 0, stream>>>(enc, flag);
    embed_kernel<<<nElem / 256, 256, 0, stream>>>(dec, W_tgt, b_tgt, x, flag);
    conv_kernel<<<nElem / 256, 256, 0, stream>>>(enc, enc_f, flag);

    dim3 gProj(D_ / 64, NTOK / 64, 3);          // (4,64,3)
    dim3 gOne(D_ / 64, NTOK / 64, 1);           // (4,64,1)
    dim3 gFF1(DFF_ / 64, NTOK / 64, 1);         // (16,64,1)
    dim3 gAttn(LD_ / 64, H_, B_);               // (16,8,4)

    for (int i = 0; i < NL_; ++i) {
        const size_t wOff  = (size_t)i * D_ * D_;      // element offsets
        const size_t bOff  = (size_t)i * D_;
        const size_t f1Off = (size_t)i * D_ * DFF_;
        const size_t f1bOff= (size_t)i * DFF_;

        add_pe_kernel<<<nElem / 256, 256, 0, stream>>>(x);

        // --- self attention ---
        gemm3_kernel<<<gProj, 256, 0, stream>>>(
            x, x, x, sa_Wq, sa_Wk, sa_Wv, sa_bq, sa_bk, sa_bv,
            q, k, v, wOff, bOff, NTOK, D_, D_, 0, flag);
        fattn_mfma_kernel<<<gAttn, 256, 0, stream>>>(q, k, v, ctx, dec_masks, 1);
        gemm3_kernel<<<gOne, 256, 0, stream>>>(
            ctx, ctx, ctx, sa_Wo, sa_Wo, sa_Wo, sa_bo, sa_bo, sa_bo,
            t, t, t, wOff, bOff, NTOK, D_, D_, 0, flag);
        ln_res_kernel<<<NTOK, 256, 0, stream>>>(t, x, sa_ln_g, sa_ln_b, bOff, flag);

        // --- cross attention ---
        gemm3_kernel<<<gProj, 256, 0, stream>>>(
            x, enc_f, enc_f, ca_Wq, ca_Wk, ca_Wv, ca_bq, ca_bk, ca_bv,
            q, k, v, wOff, bOff, NTOK, D_, D_, 0, flag);
        fattn_mfma_kernel<<<gAttn, 256, 0, stream>>>(q, k, v, ctx, enc_masks, 0);
        gemm3_kernel<<<gOne, 256, 0, stream>>>(
            ctx, ctx, ctx, ca_Wo, ca_Wo, ca_Wo, ca_bo, ca_bo, ca_bo,
            t, t, t, wOff, bOff, NTOK, D_, D_, 0, flag);
        ln_res_kernel<<<NTOK, 256, 0, stream>>>(t, x, ca_ln_g, ca_ln_b, bOff, flag);

        // --- FFN ---
        gemm3_kernel<<<gFF1, 256, 0, stream>>>(
            x, x, x, ff_W1, ff_W1, ff_W1, ff_b1, ff_b1, ff_b1,
            h, h, h, f1Off, f1bOff, NTOK, DFF_, D_, 1, flag);
        gemm3_kernel<<<gOne, 256, 0, stream>>>(
            h, h, h, ff_W2, ff_W2, ff_W2, ff_b2, ff_b2, ff_b2,
            t, t, t, f1Off, bOff, NTOK, D_, DFF_, 0, flag);
        ln_res_kernel<<<NTOK, 256, 0, stream>>>(t, x, ff_ln_g, ff_ln_b, bOff, flag);
    }

    cast_kernel<<<nElem / 256, 256, 0, stream>>>(x, d_out, flag);
}

// Round 2
// 1352.504 us; speedup vs baseline: 2.6361x; 1.5095x over previous
//
#include <hip/hip_runtime.h>
#include <hip/hip_bf16.h>

#define B_   4
#define LD_  1024
#define LE_  1024
#define D_   256
#define H_   8
#define DK_  32
#define DFF_ 1024
#define NL_  6
#define NTOK (B_ * LD_)   // 4096 decoder tokens; encoder also 4*1024 = 4096

typedef __hip_bfloat16 bf16;
typedef __bf16 bf16_t;
typedef bf16_t bf16x8 __attribute__((ext_vector_type(8)));
typedef bf16_t bf16x4 __attribute__((ext_vector_type(4)));
typedef float  f32x4  __attribute__((ext_vector_type(4)));

__device__ __forceinline__ float bits2f(unsigned short u) {
    union { unsigned int i; float f; } w; w.i = ((unsigned int)u) << 16; return w.f;
}
// dtype-flexible scalar load from tensor base + element index
__device__ __forceinline__ float ldx(const void* p, size_t i, int f32) {
    if (f32) return ((const float*)p)[i];
    return bits2f(((const unsigned short*)p)[i]);
}

// ---------------------------------------------------------------------------
// Detect input dtype (bf16 vs fp32). flag: 1=fp32, 0=bf16.
__global__ __launch_bounds__(256) void detect_kernel(
    const void* __restrict__ enc, int* __restrict__ flag)
{
    __shared__ int bad;
    if (threadIdx.x == 0) bad = 0;
    __syncthreads();
    const unsigned short* u = (const unsigned short*)enc;
    int b = 0;
    for (int i = threadIdx.x; i < 4096; i += 256) {
        unsigned short e = (u[i] >> 7) & 0xFF;
        if (e >= 142) b = 1;
    }
    if (b) atomicOr(&bad, 1);
    __syncthreads();
    if (threadIdx.x == 0) *flag = bad;
}

// ---------------------------------------------------------------------------
__global__ __launch_bounds__(256) void embed_kernel(
    const void* __restrict__ dec, const void* __restrict__ Wt,
    const void* __restrict__ bt, float* __restrict__ x, const int* __restrict__ flag)
{
    int f32 = *flag;
    int i = blockIdx.x * 256 + threadIdx.x;     // over NTOK * D_
    int d = i & (D_ - 1);
    int t = i >> 8;
    float a0 = ldx(dec, t * 3 + 0, f32);
    float a1 = ldx(dec, t * 3 + 1, f32);
    float a2 = ldx(dec, t * 3 + 2, f32);
    x[i] = ldx(bt, d, f32) + a0 * ldx(Wt, 0 * D_ + d, f32)
         + a1 * ldx(Wt, 1 * D_ + d, f32) + a2 * ldx(Wt, 2 * D_ + d, f32);
}

__global__ __launch_bounds__(256) void conv_kernel(
    const void* __restrict__ in, float* __restrict__ out, const int* __restrict__ flag)
{
    int f32 = *flag;
    int i = blockIdx.x * 256 + threadIdx.x;
    out[i] = ldx(in, i, f32);
}

__global__ __launch_bounds__(256) void add_pe_kernel(float* __restrict__ x)
{
    int i = blockIdx.x * 256 + threadIdx.x;
    int d = i & (D_ - 1);
    int tok = i >> 8;
    int pos = tok & (LD_ - 1);
    int j = d & 127;
    float inv = powf(10000.0f, -2.0f * (float)j / (float)D_);
    float s = (float)pos * inv;
    float pe = (d < 128) ? sinf(s) : cosf(s);
    x[i] += pe;
}

// ---------------------------------------------------------------------------
// MFMA GEMM: C = A @ W + bias (optional relu). A fp32 [M,K]; W,bias dtype per
// flag; wOff/bOff = element offsets of the layer slice. z-batched over up to 3
// independent (A,W,bias,C) tuples.
//
// Numerics: split-bf16 (hi/lo) on BOTH A and W -> Ah·Wh + Al·Wh + Ah·Wl gives
// fp32-equivalent products (rel err ~2^-16); accumulation fp32 in MFMA.
//
// Tiling: BM=32, BN=64, BK=32; 256 thr = 4 waves (2 row x 2 col), each wave
// computes 16x32 = two 16x16 fragments, 6 MFMA per K-step.
// LDS: A hi/lo [32][40] (20-word stride: conflict-free b128); W transposed
// hi/lo [64][40] with XOR swizzle on the 16B k-block (kb ^= (n>>3)&3) so both
// staging writes and fragment reads are 2-way (free).
// Global loads for step k+1 are prefetched into regs before computing step k.
__global__ __launch_bounds__(256) void gemm3_kernel(
    const float* __restrict__ A0, const float* __restrict__ A1, const float* __restrict__ A2,
    const void* __restrict__ W0, const void* __restrict__ W1, const void* __restrict__ W2,
    const void* __restrict__ bias0, const void* __restrict__ bias1, const void* __restrict__ bias2,
    float* __restrict__ C0, float* __restrict__ C1, float* __restrict__ C2,
    size_t wOff, size_t bOff,
    int M, int N, int K, int relu, const int* __restrict__ flag)
{
    const int f32 = *flag;
    const int z = blockIdx.z;
    const float* A = (z == 0) ? A0 : (z == 1) ? A1 : A2;
    const void*  W = (z == 0) ? W0 : (z == 1) ? W1 : W2;
    const void*  bias = (z == 0) ? bias0 : (z == 1) ? bias1 : bias2;
    float* C = (z == 0) ? C0 : (z == 1) ? C1 : C2;

    __shared__ __align__(16) bf16_t Ahi[32][40];
    __shared__ __align__(16) bf16_t Alo[32][40];
    __shared__ __align__(16) bf16_t Whi[64][40];
    __shared__ __align__(16) bf16_t Wlo[64][40];

    const int tid = threadIdx.x;
    const int m0 = blockIdx.y * 32, n0 = blockIdx.x * 64;
    const int w = tid >> 6, l = tid & 63, l15 = l & 15, lg = l >> 4;
    const int wr = w >> 1, wc = w & 1;

    // A staging: thread -> (row 0..31, 4-float group)
    const int ar = tid >> 3, ac = (tid & 7) * 4;
    // W staging: thread -> (col n 0..63, k-block 0..3); swizzled block index
    const int wn = tid & 63, wkg = tid >> 6;
    const int wkb = 8 * (wkg ^ ((wn >> 3) & 3));

    // fragment read indices (hoisted)
    const int fa = 16 * wr + l15;
    const int c0 = 32 * wc + l15, c1 = c0 + 16;
    const int kb0 = 8 * (lg ^ ((c0 >> 3) & 3));
    const int kb1 = 8 * (lg ^ ((c1 >> 3) & 3));

    f32x4 acc0 = {0.f, 0.f, 0.f, 0.f};
    f32x4 acc1 = {0.f, 0.f, 0.f, 0.f};

    // prefetch K-step 0
    float4 av = *(const float4*)&A[(size_t)(m0 + ar) * K + ac];
    float wf[8];
#pragma unroll
    for (int j = 0; j < 8; ++j)
        wf[j] = ldx(W, wOff + (size_t)(8 * wkg + j) * N + n0 + wn, f32);

    for (int k0 = 0; k0 < K; k0 += 32) {
        __syncthreads();
        {   // convert staged regs -> hi/lo LDS
            float af[4] = {av.x, av.y, av.z, av.w};
            bf16x4 h4, l4;
#pragma unroll
            for (int j = 0; j < 4; ++j) {
                bf16_t hv = (bf16_t)af[j];
                h4[j] = hv;
                l4[j] = (bf16_t)(af[j] - (float)hv);
            }
            *(bf16x4*)&Ahi[ar][ac] = h4;
            *(bf16x4*)&Alo[ar][ac] = l4;
            bf16x8 h8, l8;
#pragma unroll
            for (int j = 0; j < 8; ++j) {
                bf16_t hv = (bf16_t)wf[j];
                h8[j] = hv;
                l8[j] = (bf16_t)(wf[j] - (float)hv);
            }
            *(bf16x8*)&Whi[wn][wkb] = h8;
            *(bf16x8*)&Wlo[wn][wkb] = l8;
        }
        __syncthreads();

        // prefetch next K-step while MFMAs run
        if (k0 + 32 < K) {
            av = *(const float4*)&A[(size_t)(m0 + ar) * K + k0 + 32 + ac];
#pragma unroll
            for (int j = 0; j < 8; ++j)
                wf[j] = ldx(W, wOff + (size_t)(k0 + 32 + 8 * wkg + j) * N + n0 + wn, f32);
        }

        bf16x8 ah = *(const bf16x8*)&Ahi[fa][8 * lg];
        bf16x8 al = *(const bf16x8*)&Alo[fa][8 * lg];
        bf16x8 bh0 = *(const bf16x8*)&Whi[c0][kb0];
        bf16x8 bl0 = *(const bf16x8*)&Wlo[c0][kb0];
        bf16x8 bh1 = *(const bf16x8*)&Whi[c1][kb1];
        bf16x8 bl1 = *(const bf16x8*)&Wlo[c1][kb1];
        acc0 = __builtin_amdgcn_mfma_f32_16x16x32_bf16(ah, bh0, acc0, 0, 0, 0);
        acc0 = __builtin_amdgcn_mfma_f32_16x16x32_bf16(al, bh0, acc0, 0, 0, 0);
        acc0 = __builtin_amdgcn_mfma_f32_16x16x32_bf16(ah, bl0, acc0, 0, 0, 0);
        acc1 = __builtin_amdgcn_mfma_f32_16x16x32_bf16(ah, bh1, acc1, 0, 0, 0);
        acc1 = __builtin_amdgcn_mfma_f32_16x16x32_bf16(al, bh1, acc1, 0, 0, 0);
        acc1 = __builtin_amdgcn_mfma_f32_16x16x32_bf16(ah, bl1, acc1, 0, 0, 0);
    }

    // epilogue: C/D layout col=l15, row=4*lg+r
    const int cm = m0 + 16 * wr + 4 * lg;
    const int cn = n0 + 32 * wc + l15;
    const float b0v = ldx(bias, bOff + cn, f32);
    const float b1v = ldx(bias, bOff + cn + 16, f32);
#pragma unroll
    for (int r = 0; r < 4; ++r) {
        float v0 = acc0[r] + b0v;
        float v1 = acc1[r] + b1v;
        if (relu) { v0 = fmaxf(v0, 0.f); v1 = fmaxf(v1, 0.f); }
        C[(size_t)(cm + r) * N + cn]      = v0;
        C[(size_t)(cm + r) * N + cn + 16] = v1;
    }
}

// ---------------------------------------------------------------------------
// MFMA flash attention. One block per (64-q-row tile, head, batch).
// grid = (LD/64, H, B), 256 threads = 4 waves; wave w owns q rows w*16..w*16+15.
__global__ __launch_bounds__(256) void fattn_mfma_kernel(
    const float* __restrict__ Q, const float* __restrict__ K,
    const float* __restrict__ V, float* __restrict__ O,
    const int* __restrict__ mask, int causal)
{
    __shared__ __align__(16) bf16_t Khi[64][40];
    __shared__ __align__(16) bf16_t Klo[64][40];
    __shared__ __align__(16) bf16_t Vt[32][72];
    __shared__ __align__(16) float Ps[4][16][68];
    __shared__ int smask[64];

    const int tid = threadIdx.x;
    const int qt = blockIdx.x, h = blockIdx.y, b = blockIdx.z;
    const int w   = tid >> 6;        // wave 0..3
    const int l   = tid & 63;
    const int l15 = l & 15;
    const int lg  = l >> 4;          // 0..3

    const int lr = tid >> 2;         // 0..63
    const int lc = (tid & 3) * 8;    // 0,8,16,24

    const float scale = 0.17677669529663687f;   // 1/sqrt(32)
    bf16x8 qhi, qlo;
    {
        const float* qp = Q + ((size_t)(b * LD_ + qt * 64 + w * 16 + l15)) * D_ + h * DK_ + 8 * lg;
        float4 qa = *(const float4*)qp;
        float4 qb = *(const float4*)(qp + 4);
        float qf[8] = {qa.x, qa.y, qa.z, qa.w, qb.x, qb.y, qb.z, qb.w};
#pragma unroll
        for (int j = 0; j < 8; ++j) {
            float xv = qf[j] * scale;
            bf16_t hv = (bf16_t)xv;
            qhi[j] = hv;
            qlo[j] = (bf16_t)(xv - (float)hv);
        }
    }

    float mrow[4], lsum[4];
#pragma unroll
    for (int r = 0; r < 4; ++r) { mrow[r] = -3.0e38f; lsum[r] = 0.0f; }
    f32x4 o0 = {0.f, 0.f, 0.f, 0.f};
    f32x4 o1 = {0.f, 0.f, 0.f, 0.f};

    const int nkt = causal ? (qt + 1) : (LE_ / 64);

    for (int kt = 0; kt < nkt; ++kt) {
        __syncthreads();
        {
            const float* kp = K + ((size_t)(b * LE_ + kt * 64 + lr)) * D_ + h * DK_ + lc;
            const float* vp = V + ((size_t)(b * LE_ + kt * 64 + lr)) * D_ + h * DK_ + lc;
            float4 ka = *(const float4*)kp;
            float4 kb = *(const float4*)(kp + 4);
            float kf[8] = {ka.x, ka.y, ka.z, ka.w, kb.x, kb.y, kb.z, kb.w};
            bf16x8 khv, klv;
#pragma unroll
            for (int j = 0; j < 8; ++j) {
                bf16_t hv = (bf16_t)kf[j];
                khv[j] = hv;
                klv[j] = (bf16_t)(kf[j] - (float)hv);
            }
            *(bf16x8*)&Khi[lr][lc] = khv;
            *(bf16x8*)&Klo[lr][lc] = klv;
            float4 va = *(const float4*)vp;
            float4 vb = *(const float4*)(vp + 4);
            float vf[8] = {va.x, va.y, va.z, va.w, vb.x, vb.y, vb.z, vb.w};
#pragma unroll
            for (int j = 0; j < 8; ++j)
                Vt[lc + j][lr] = (bf16_t)vf[j];
            if (tid < 64) smask[tid] = mask[b * 1024 + kt * 64 + tid];
        }
        __syncthreads();

        // S = Q·K^T (split bf16)
        f32x4 s[4];
#pragma unroll
        for (int nt = 0; nt < 4; ++nt) {
            bf16x8 kh = *(const bf16x8*)&Khi[nt * 16 + l15][8 * lg];
            bf16x8 kl = *(const bf16x8*)&Klo[nt * 16 + l15][8 * lg];
            f32x4 acc = {0.f, 0.f, 0.f, 0.f};
            acc = __builtin_amdgcn_mfma_f32_16x16x32_bf16(qhi, kh, acc, 0, 0, 0);
            acc = __builtin_amdgcn_mfma_f32_16x16x32_bf16(qhi, kl, acc, 0, 0, 0);
            acc = __builtin_amdgcn_mfma_f32_16x16x32_bf16(qlo, kh, acc, 0, 0, 0);
            s[nt] = acc;
        }

        const int row0 = qt * 64 + w * 16 + 4 * lg;
        float pm[4] = {-3.0e38f, -3.0e38f, -3.0e38f, -3.0e38f};
#pragma unroll
        for (int nt = 0; nt < 4; ++nt) {
            int col = kt * 64 + nt * 16 + l15;
            int msk = smask[nt * 16 + l15];
#pragma unroll
            for (int r = 0; r < 4; ++r) {
                bool dead = (msk != 0) || (causal && col > row0 + r);
                float v = dead ? -1e30f : s[nt][r];
                s[nt][r] = v;
                pm[r] = fmaxf(pm[r], v);
            }
        }
#pragma unroll
        for (int r = 0; r < 4; ++r) {
            pm[r] = fmaxf(pm[r], __shfl_xor(pm[r], 1));
            pm[r] = fmaxf(pm[r], __shfl_xor(pm[r], 2));
            pm[r] = fmaxf(pm[r], __shfl_xor(pm[r], 4));
            pm[r] = fmaxf(pm[r], __shfl_xor(pm[r], 8));
        }
        float alpha[4], psum[4];
#pragma unroll
        for (int r = 0; r < 4; ++r) {
            float mnew = fmaxf(mrow[r], pm[r]);
            alpha[r] = __expf(mrow[r] - mnew);
            mrow[r] = mnew;
            psum[r] = 0.0f;
        }
#pragma unroll
        for (int nt = 0; nt < 4; ++nt) {
#pragma unroll
            for (int r = 0; r < 4; ++r) {
                float p = __expf(s[nt][r] - mrow[r]);
                Ps[w][4 * lg + r][nt * 16 + l15] = p;
                psum[r] += p;
            }
        }
#pragma unroll
        for (int r = 0; r < 4; ++r) {
            psum[r] += __shfl_xor(psum[r], 1);
            psum[r] += __shfl_xor(psum[r], 2);
            psum[r] += __shfl_xor(psum[r], 4);
            psum[r] += __shfl_xor(psum[r], 8);
            lsum[r] = lsum[r] * alpha[r] + psum[r];
            o0[r] *= alpha[r];
            o1[r] *= alpha[r];
        }

        // O += P·V (P transposed through wave-private LDS)
#pragma unroll
        for (int pass = 0; pass < 2; ++pass) {
            const float* pr = &Ps[w][l15][pass * 32 + 8 * lg];
            f32x4 pa0 = *(const f32x4*)pr;
            f32x4 pa1 = *(const f32x4*)(pr + 4);
            bf16x8 pa;
#pragma unroll
            for (int j = 0; j < 4; ++j) {
                pa[j]     = (bf16_t)pa0[j];
                pa[4 + j] = (bf16_t)pa1[j];
            }
            bf16x8 vb0 = *(const bf16x8*)&Vt[l15][pass * 32 + 8 * lg];
            bf16x8 vb1 = *(const bf16x8*)&Vt[16 + l15][pass * 32 + 8 * lg];
            o0 = __builtin_amdgcn_mfma_f32_16x16x32_bf16(pa, vb0, o0, 0, 0, 0);
            o1 = __builtin_amdgcn_mfma_f32_16x16x32_bf16(pa, vb1, o1, 0, 0, 0);
        }
    }

    float inv[4];
#pragma unroll
    for (int r = 0; r < 4; ++r) inv[r] = 1.0f / lsum[r];
    float* op = O + ((size_t)(b * LD_ + qt * 64 + w * 16 + 4 * lg)) * D_ + h * DK_ + l15;
#pragma unroll
    for (int r = 0; r < 4; ++r) {
        op[(size_t)r * D_ + 0]  = o0[r] * inv[r];
        op[(size_t)r * D_ + 16] = o1[r] * inv[r];
    }
}

// ---------------------------------------------------------------------------
// x = LayerNorm(t + x) * g + b ; g/b dtype per flag, gbOff = element offset
__global__ __launch_bounds__(256) void ln_res_kernel(
    const float* __restrict__ t, float* __restrict__ x,
    const void* __restrict__ g, const void* __restrict__ bt,
    size_t gbOff, const int* __restrict__ flag)
{
    __shared__ float r1[256];
    __shared__ float r2[256];
    int f32 = *flag;
    int tok = blockIdx.x;
    int d = threadIdx.x;
    size_t idx = (size_t)tok * D_ + d;
    float v = t[idx] + x[idx];
    r1[d] = v; r2[d] = v * v;
    __syncthreads();
    for (int off = 128; off > 0; off >>= 1) {
        if (d < off) { r1[d] += r1[d + off]; r2[d] += r2[d + off]; }
        __syncthreads();
    }
    float mean = r1[0] * (1.0f / 256.0f);
    float var  = r2[0] * (1.0f / 256.0f) - mean * mean;
    float inv  = 1.0f / sqrtf(var + 1e-5f);
    x[idx] = (v - mean) * inv * ldx(g, gbOff + d, f32) + ldx(bt, gbOff + d, f32);
}

__global__ __launch_bounds__(256) void cast_kernel(
    const float* __restrict__ x, void* __restrict__ out, const int* __restrict__ flag)
{
    int f32 = *flag;
    int i = blockIdx.x * 256 + threadIdx.x;
    if (f32) ((float*)out)[i] = x[i];
    else ((bf16*)out)[i] = __float2bfloat16(x[i]);
}

// ---------------------------------------------------------------------------
extern "C" void kernel_launch(void* const* d_in, const int* in_sizes, int n_in,
                              void* d_out, int out_size, void* d_ws, size_t ws_size,
                              hipStream_t stream)
{
    const void* enc       = d_in[0];
    const void* dec       = d_in[1];
    const int*  enc_masks = (const int*)d_in[2];
    const int*  dec_masks = (const int*)d_in[3];
    const void* W_tgt = d_in[4];
    const void* b_tgt = d_in[5];
    const void* sa_Wq = d_in[6];
    const void* sa_bq = d_in[7];
    const void* sa_Wk = d_in[8];
    const void* sa_bk = d_in[9];
    const void* sa_Wv = d_in[10];
    const void* sa_bv = d_in[11];
    const void* sa_Wo = d_in[12];
    const void* sa_bo = d_in[13];
    const void* sa_ln_g = d_in[14];
    const void* sa_ln_b = d_in[15];
    const void* ca_Wq = d_in[16];
    const void* ca_bq = d_in[17];
    const void* ca_Wk = d_in[18];
    const void* ca_bk = d_in[19];
    const void* ca_Wv = d_in[20];
    const void* ca_bv = d_in[21];
    const void* ca_Wo = d_in[22];
    const void* ca_bo = d_in[23];
    const void* ca_ln_g = d_in[24];
    const void* ca_ln_b = d_in[25];
    const void* ff_W1 = d_in[26];
    const void* ff_b1 = d_in[27];
    const void* ff_W2 = d_in[28];
    const void* ff_b2 = d_in[29];
    const void* ff_ln_g = d_in[30];
    const void* ff_ln_b = d_in[31];

    const size_t M1 = (size_t)NTOK * D_;        // 1M floats
    float* ws = (float*)d_ws;
    float* x     = ws;
    float* q     = ws + 1 * M1;
    float* k     = ws + 2 * M1;
    float* v     = ws + 3 * M1;
    float* ctx   = ws + 4 * M1;
    float* t     = ws + 5 * M1;
    float* h     = ws + 6 * M1;                 // 4M floats (NTOK x DFF)
    float* enc_f = ws + 10 * M1;
    int*   flag  = (int*)(ws + 11 * M1);

    const int nElem = NTOK * D_;                // 1,048,576

    detect_kernel<<<1, 256, 0, stream>>>(enc, flag);
    embed_kernel<<<nElem / 256, 256, 0, stream>>>(dec, W_tgt, b_tgt, x, flag);
    conv_kernel<<<nElem / 256, 256, 0, stream>>>(enc, enc_f, flag);

    dim3 gProj(D_ / 64, NTOK / 32, 3);          // (4,128,3)
    dim3 gOne(D_ / 64, NTOK / 32, 1);           // (4,128,1)
    dim3 gFF1(DFF_ / 64, NTOK / 32, 1);         // (16,128,1)
    dim3 gAttn(LD_ / 64, H_, B_);               // (16,8,4)

    for (int i = 0; i < NL_; ++i) {
        const size_t wOff  = (size_t)i * D_ * D_;      // element offsets
        const size_t bOff  = (size_t)i * D_;
        const size_t f1Off = (size_t)i * D_ * DFF_;
        const size_t f1bOff= (size_t)i * DFF_;

        add_pe_kernel<<<nElem / 256, 256, 0, stream>>>(x);

        // --- self attention ---
        gemm3_kernel<<<gProj, 256, 0, stream>>>(
            x, x, x, sa_Wq, sa_Wk, sa_Wv, sa_bq, sa_bk, sa_bv,
            q, k, v, wOff, bOff, NTOK, D_, D_, 0, flag);
        fattn_mfma_kernel<<<gAttn, 256, 0, stream>>>(q, k, v, ctx, dec_masks, 1);
        gemm3_kernel<<<gOne, 256, 0, stream>>>(
            ctx, ctx, ctx, sa_Wo, sa_Wo, sa_Wo, sa_bo, sa_bo, sa_bo,
            t, t, t, wOff, bOff, NTOK, D_, D_, 0, flag);
        ln_res_kernel<<<NTOK, 256, 0, stream>>>(t, x, sa_ln_g, sa_ln_b, bOff, flag);

        // --- cross attention ---
        gemm3_kernel<<<gProj, 256, 0, stream>>>(
            x, enc_f, enc_f, ca_Wq, ca_Wk, ca_Wv, ca_bq, ca_bk, ca_bv,
            q, k, v, wOff, bOff, NTOK, D_, D_, 0, flag);
        fattn_mfma_kernel<<<gAttn, 256, 0, stream>>>(q, k, v, ctx, enc_masks, 0);
        gemm3_kernel<<<gOne, 256, 0, stream>>>(
            ctx, ctx, ctx, ca_Wo, ca_Wo, ca_Wo, ca_bo, ca_bo, ca_bo,
            t, t, t, wOff, bOff, NTOK, D_, D_, 0, flag);
        ln_res_kernel<<<NTOK, 256, 0, stream>>>(t, x, ca_ln_g, ca_ln_b, bOff, flag);

        // --- FFN ---
        gemm3_kernel<<<gFF1, 256, 0, stream>>>(
            x, x, x, ff_W1, ff_W1, ff_W1, ff_b1, ff_b1, ff_b1,
            h, h, h, f1Off, f1bOff, NTOK, DFF_, D_, 1, flag);
        gemm3_kernel<<<gOne, 256, 0, stream>>>(
            h, h, h, ff_W2, ff_W2, ff_W2, ff_b2, ff_b2, ff_b2,
            t, t, t, f1Off, bOff, NTOK, D_, DFF_, 0, flag);
        ln_res_kernel<<<NTOK, 256, 0, stream>>>(t, x, ff_ln_g, ff_ln_b, bOff, flag);
    }

    cast_kernel<<<nElem / 256, 256, 0, stream>>>(x, d_out, flag);
}